// Round 2
// baseline (554.593 us; speedup 1.0000x reference)
//
#include <hip/hip_runtime.h>

#define NN 100000
#define MM 8
#define KK 256
#define DD 64
#define BROWS 128
#define NTILES ((NN + BROWS - 1) / BROWS)   // 782

typedef _Float16 half8 __attribute__((ext_vector_type(8)));
typedef float    f32x4 __attribute__((ext_vector_type(4)));

// ---------------------------------------------------------------------------
// ws layout (bytes):
//   [0,      256K)  cb_hi  half8[MM*8*256]   chunk-major: idx = m*2048 + c*256 + k
//   [256K,   512K)  cb_lo  (scaled x2048)
//   [512K,   520K)  csq    float[MM*KK]
// ---------------------------------------------------------------------------

__global__ __launch_bounds__(256) void pq_prep_kernel(
    const float* __restrict__ cb, half8* __restrict__ whi,
    half8* __restrict__ wlo, float* __restrict__ csq)
{
    const int t = blockIdx.x * 256 + threadIdx.x;      // 0..16383
    const int m = t >> 11, rest = t & 2047;
    const int c = rest >> 8, k = rest & 255;
    const float* src = cb + ((size_t)(m * KK + k)) * DD + c * 8;
    half8 h, l;
#pragma unroll
    for (int j = 0; j < 8; ++j) {
        float v = src[j];
        _Float16 hi = (_Float16)v;
        h[j] = hi;
        l[j] = (_Float16)((v - (float)hi) * 2048.0f);
    }
    whi[t] = h;
    wlo[t] = l;

    if (t < MM * KK) {
        const float* cr = cb + (size_t)t * DD;
        float s0 = 0.f, s1 = 0.f, s2 = 0.f, s3 = 0.f;
#pragma unroll
        for (int d = 0; d < DD; d += 4) {
            s0 = fmaf(cr[d + 0], cr[d + 0], s0);
            s1 = fmaf(cr[d + 1], cr[d + 1], s1);
            s2 = fmaf(cr[d + 2], cr[d + 2], s2);
            s3 = fmaf(cr[d + 3], cr[d + 3], s3);
        }
        csq[t] = (s0 + s1) + (s2 + s3);
    }
}

// Main: block = 128 rows x 1 m x 256 k. MFMA fp16-split distances; rows whose
// top-2 MFMA distances are within DELTA get an exact fp32 rescore (identical
// arithmetic to the verified kernel, absmax 0).
//
// R2: latency-bound diagnosis (per-wave lifetime 61K cyc vs 8K issue cyc,
// occupancy register-tier-capped at ~16 waves/CU). Deepen the software
// pipeline: B-fragment prefetch depth 1 -> 2 (loads span ~2 full k-bodies),
// and split the acc2 4-deep dependent MFMA chain into two 2-deep chains.
// Stays inside the 128-reg / 4-wave tier. Arithmetic + k-visit order and
// all rounding identical: acc2a+acc2b merge order (a then b) matches the
// previous sequential accumulation order? NOTE: previous code accumulated
// Ah*bl0, Ah*bl1, Al*bh0, Al*bh1 into ONE chain; fp32 MFMA accumulate is
// exact per-step fma into f32, reassociation across the two chains changes
// the sum order -> tiny fp difference in acc2, covered by DELTA rescore
// margin (DELTA=4e-3 vs fp16-path error budget; the split changes acc2 by
// <1 ulp-of-partial-sums, orders of magnitude below DELTA).
#define DELTA 4.0e-3f

__global__ __launch_bounds__(256, 4) void pq_main_kernel(
    const float* __restrict__ x, const half8* __restrict__ whi,
    const half8* __restrict__ wlo, const float* __restrict__ csqg,
    const float* __restrict__ cbf, float* __restrict__ qout,
    float* __restrict__ idout)
{
    __shared__ float csq_s[KK];     // 1 KB
    __shared__ int   cand_k[BROWS]; // 512 B

    const int m   = blockIdx.y;
    const int n0  = blockIdx.x * BROWS;
    const int tid = threadIdx.x;
    const int w = tid >> 6, L = tid & 63;
    const int q = L >> 4, ci = L & 15;

    csq_s[tid] = csqg[m * KK + tid];

    // A fragments: d = t*32 + q*8 + j on BOTH operands -> k-slot permutation
    // cancels (same mapping on A and B).
    half8 Ah[2][2], Al[2][2];
#pragma unroll
    for (int rb = 0; rb < 2; ++rb) {
        int n = n0 + w * 32 + rb * 16 + ci;
        if (n > NN - 1) n = NN - 1;                    // tail clamp (writes guarded)
        const float4* xp = (const float4*)(x + (size_t)n * (MM * DD) + m * DD);
#pragma unroll
        for (int t = 0; t < 2; ++t) {
            float4 v0 = xp[t * 8 + q * 2 + 0];
            float4 v1 = xp[t * 8 + q * 2 + 1];
            float vs[8] = {v0.x, v0.y, v0.z, v0.w, v1.x, v1.y, v1.z, v1.w};
#pragma unroll
            for (int j = 0; j < 8; ++j) {
                _Float16 hi = (_Float16)vs[j];
                Ah[rb][t][j] = hi;
                Al[rb][t][j] = (_Float16)((vs[j] - (float)hi) * 2048.0f);
            }
        }
    }

    // per-lane best (d1,k1) and second-best value d2, per output row slot
    float d1v[2][4], d2v[2][4];
    int   k1v[2][4];
#pragma unroll
    for (int rb = 0; rb < 2; ++rb)
#pragma unroll
        for (int r = 0; r < 4; ++r) { d1v[rb][r] = 3.4e38f; d2v[rb][r] = 3.4e38f; k1v[rb][r] = 0; }

    // Per-lane B fragment pointers: c-chunk = q (low 32 dims) and 4+q (high).
    const half8* bh0p = whi + m * 2048 + q * 256;
    const half8* bh1p = whi + m * 2048 + (4 + q) * 256;
    const half8* bl0p = wlo + m * 2048 + q * 256;
    const half8* bl1p = wlo + m * 2048 + (4 + q) * 256;

    __syncthreads();                                   // csq_s ready

    // depth-2 pipeline: slot (kt&1) holds fragments for iteration kt
    half8 Bh0[2], Bh1[2], Bl0[2], Bl1[2];
#pragma unroll
    for (int p = 0; p < 2; ++p) {
        const int o = p * 16 + ci;
        Bh0[p] = bh0p[o]; Bh1[p] = bh1p[o];
        Bl0[p] = bl0p[o]; Bl1[p] = bl1p[o];
    }

#pragma unroll
    for (int kt = 0; kt < 16; ++kt) {
        const int cur = kt & 1;
        // prefetch kt+2 (tail: harmless reload of current data, L1-hit)
        const int kn = (kt + 2 < 16) ? (kt + 2) : kt;
        const int o = kn * 16 + ci;
        half8 nh0 = bh0p[o], nh1 = bh1p[o], nl0 = bl0p[o], nl1 = bl1p[o];

        f32x4 acc1[2], acc2a[2], acc2b[2];
        const f32x4 z = {0.f, 0.f, 0.f, 0.f};
        acc1[0] = z; acc1[1] = z;
        acc2a[0] = z; acc2a[1] = z;
        acc2b[0] = z; acc2b[1] = z;
#pragma unroll
        for (int rb = 0; rb < 2; ++rb) {
            acc1[rb]  = __builtin_amdgcn_mfma_f32_16x16x32_f16(Ah[rb][0], Bh0[cur], acc1[rb],  0, 0, 0);
            acc1[rb]  = __builtin_amdgcn_mfma_f32_16x16x32_f16(Ah[rb][1], Bh1[cur], acc1[rb],  0, 0, 0);
            acc2a[rb] = __builtin_amdgcn_mfma_f32_16x16x32_f16(Ah[rb][0], Bl0[cur], acc2a[rb], 0, 0, 0);
            acc2a[rb] = __builtin_amdgcn_mfma_f32_16x16x32_f16(Ah[rb][1], Bl1[cur], acc2a[rb], 0, 0, 0);
            acc2b[rb] = __builtin_amdgcn_mfma_f32_16x16x32_f16(Al[rb][0], Bh0[cur], acc2b[rb], 0, 0, 0);
            acc2b[rb] = __builtin_amdgcn_mfma_f32_16x16x32_f16(Al[rb][1], Bh1[cur], acc2b[rb], 0, 0, 0);
        }

        // dist(sans xsq) = csq - 2*(acc1 + (acc2a+acc2b)/2048)
        // C/D: col=lane&15, row=q*4+r
        const int k = kt * 16 + ci;
        const float cq = csq_s[k];
#pragma unroll
        for (int rb = 0; rb < 2; ++rb)
#pragma unroll
            for (int r = 0; r < 4; ++r) {
                float lo = acc2a[rb][r] + acc2b[rb][r];
                float cross = acc1[rb][r] + lo * (1.0f / 2048.0f);
                float d = cq - 2.0f * cross;
                if (d < d1v[rb][r]) {
                    d2v[rb][r] = d1v[rb][r];
                    d1v[rb][r] = d; k1v[rb][r] = k;
                } else if (d < d2v[rb][r]) {
                    d2v[rb][r] = d;
                }
            }

        Bh0[cur] = nh0; Bh1[cur] = nh1; Bl0[cur] = nl0; Bl1[cur] = nl1;
    }

    // Finalize each of the 8 row-slots: butterfly argmin; near-ties -> exact
    // fp32 rescore (R1 arithmetic, empirically bit-matching numpy's argmin).
#pragma unroll
    for (int rb = 0; rb < 2; ++rb)
#pragma unroll
        for (int r = 0; r < 4; ++r) {
            float d = d1v[rb][r];
            int   k = k1v[rb][r];
            for (int mask = 1; mask < 16; mask <<= 1) {
                float ds = __shfl_xor(d, mask);
                int   ks = __shfl_xor(k, mask);
                if (ds < d || (ds == d && ks < k)) { d = ds; k = ks; }
            }
            const float thr = d + DELTA;               // d == dmin, uniform
            int cnt = (d1v[rb][r] <= thr ? 1 : 0) + (d2v[rb][r] <= thr ? 1 : 0);
            for (int mask = 1; mask < 16; mask <<= 1) cnt += __shfl_xor(cnt, mask);

            const int n = n0 + w * 32 + rb * 16 + q * 4 + r;
            if (cnt > 1 && n < NN) {                   // rare exact path (q-group uniform)
                const float* xr = x + (size_t)n * (MM * DD) + m * DD;
                float s0 = 0.f, s1 = 0.f, s2 = 0.f, s3 = 0.f;
                for (int dd = 0; dd < DD; dd += 4) {
                    s0 = fmaf(xr[dd + 0], xr[dd + 0], s0);
                    s1 = fmaf(xr[dd + 1], xr[dd + 1], s1);
                    s2 = fmaf(xr[dd + 2], xr[dd + 2], s2);
                    s3 = fmaf(xr[dd + 3], xr[dd + 3], s3);
                }
                const float xsq = (s0 + s1) + (s2 + s3);
                float bd = 3.4e38f; int bk = 0;
                for (int j = 0; j < 16; ++j) {         // lane ci: k = ci + 16j (ascending)
                    const int kk = ci + 16 * j;
                    const float* c0 = cbf + ((size_t)(m * KK + kk)) * DD;
                    float a0 = 0.f, a1 = 0.f;
                    for (int dd = 0; dd < DD; dd += 2) {
                        a0 = fmaf(c0[dd + 0], xr[dd + 0], a0);
                        a1 = fmaf(c0[dd + 1], xr[dd + 1], a1);
                    }
                    const float dist = (xsq - 2.f * (a0 + a1)) + csq_s[kk];
                    if (dist < bd) { bd = dist; bk = kk; }   // strict <, ascending k
                }
                for (int mask = 1; mask < 16; mask <<= 1) {
                    float db = __shfl_xor(bd, mask);
                    int   kb = __shfl_xor(bk, mask);
                    if (db < bd || (db == bd && kb < bk)) { bd = db; bk = kb; }
                }
                k = bk;
            }
            if (ci == r) cand_k[w * 32 + rb * 16 + q * 4 + r] = k;
        }
    __syncthreads();

    if (tid < BROWS) {
        int n = n0 + tid;
        if (n < NN) idout[(size_t)m * NN + n] = (float)cand_k[tid];
    }
    for (int i = 0; i < 8; ++i) {
        int row = i * 16 + (tid >> 4);
        int n = n0 + row;
        if (n < NN) {
            int k = cand_k[row];
            int j = tid & 15;
            float4 v = ((const float4*)cbf)[(m * KK + k) * 16 + j];
            ((float4*)(qout + (size_t)n * (MM * DD) + m * DD))[j] = v;
        }
    }
}

extern "C" void kernel_launch(void* const* d_in, const int* in_sizes, int n_in,
                              void* d_out, int out_size, void* d_ws, size_t ws_size,
                              hipStream_t stream)
{
    const float* x  = (const float*)d_in[0];
    const float* cb = (const float*)d_in[1];

    float* qout  = (float*)d_out;
    float* idout = qout + (size_t)NN * (MM * DD);

    half8* whi = (half8*)d_ws;
    half8* wlo = (half8*)((char*)d_ws + 256 * 1024);
    float* csq = (float*)((char*)d_ws + 512 * 1024);

    pq_prep_kernel<<<dim3(64), dim3(256), 0, stream>>>(cb, whi, wlo, csq);

    pq_main_kernel<<<dim3(NTILES, MM), dim3(256), 0, stream>>>(
        x, whi, wlo, csq, cb, qout, idout);
}

// Round 3
// 428.005 us; speedup vs baseline: 1.2958x; 1.2958x over previous
//
#include <hip/hip_runtime.h>

#define NN 100000
#define MM 8
#define KK 256
#define DD 64
#define BROWS 128
#define NTILES ((NN + BROWS - 1) / BROWS)   // 782

typedef _Float16 half8 __attribute__((ext_vector_type(8)));
typedef float    f32x4 __attribute__((ext_vector_type(4)));

// ---------------------------------------------------------------------------
// ws layout (bytes):
//   [0,      256K)  cb_hi  half8[MM*8*256]   chunk-major: idx = m*2048 + c*256 + k
//   [256K,   512K)  cb_lo  (scaled x2048)
//   [512K,   520K)  csq    float[MM*KK]
// ---------------------------------------------------------------------------

__global__ __launch_bounds__(256) void pq_prep_kernel(
    const float* __restrict__ cb, half8* __restrict__ whi,
    half8* __restrict__ wlo, float* __restrict__ csq)
{
    const int t = blockIdx.x * 256 + threadIdx.x;      // 0..16383
    const int m = t >> 11, rest = t & 2047;
    const int c = rest >> 8, k = rest & 255;
    const float* src = cb + ((size_t)(m * KK + k)) * DD + c * 8;
    half8 h, l;
#pragma unroll
    for (int j = 0; j < 8; ++j) {
        float v = src[j];
        _Float16 hi = (_Float16)v;
        h[j] = hi;
        l[j] = (_Float16)((v - (float)hi) * 2048.0f);
    }
    whi[t] = h;
    wlo[t] = l;

    if (t < MM * KK) {
        const float* cr = cb + (size_t)t * DD;
        float s0 = 0.f, s1 = 0.f, s2 = 0.f, s3 = 0.f;
#pragma unroll
        for (int d = 0; d < DD; d += 4) {
            s0 = fmaf(cr[d + 0], cr[d + 0], s0);
            s1 = fmaf(cr[d + 1], cr[d + 1], s1);
            s2 = fmaf(cr[d + 2], cr[d + 2], s2);
            s3 = fmaf(cr[d + 3], cr[d + 3], s3);
        }
        csq[t] = (s0 + s1) + (s2 + s3);
    }
}

// Main: block = 128 rows x 1 m x 256 k. MFMA fp16-split distances; rows whose
// top-2 MFMA distances are within DELTA get an exact fp32 rescore (identical
// arithmetic to the verified kernel, absmax 0).
//
// R3: R2's depth-2 pipeline regressed because the compiler left Bh0[2][cur]
// runtime-indexed -> scratch (WRITE_SIZE 203->359 MB). Same idea, made
// static-safe: 16 explicitly macro-expanded bodies, THREE named register
// sets rotating mod 3 (no arrays, no runtime indices). Load for kt+2 issues
// at top of body kt => ~2 bodies of latency cover. Arithmetic is R1's
// bit-identical single-chain form. launch_bounds(256,3) gives the allocator
// ~170 regs (matches R1's measured ~3.2 resident waves/SIMD).
#define DELTA 4.0e-3f

#define MFMA16(A, B, C) __builtin_amdgcn_mfma_f32_16x16x32_f16(A, B, C, 0, 0, 0)

// issue prefetch of k-tile KT into named set P (4 independent 16B loads)
#define PF(P, KT)                                                          \
    {                                                                      \
        const int o_ = (KT) * 16 + ci;                                     \
        P##h0 = bh0p[o_]; P##h1 = bh1p[o_];                                \
        P##l0 = bl0p[o_]; P##l1 = bl1p[o_];                                \
    }

// compute body for k-tile KT using named set P (R1-identical arithmetic)
#define BODY(P, KT)                                                        \
    {                                                                      \
        f32x4 acc1_0 = z, acc1_1 = z, acc2_0 = z, acc2_1 = z;              \
        acc1_0 = MFMA16(Ah[0][0], P##h0, acc1_0);                          \
        acc1_0 = MFMA16(Ah[0][1], P##h1, acc1_0);                          \
        acc2_0 = MFMA16(Ah[0][0], P##l0, acc2_0);                          \
        acc2_0 = MFMA16(Ah[0][1], P##l1, acc2_0);                          \
        acc2_0 = MFMA16(Al[0][0], P##h0, acc2_0);                          \
        acc2_0 = MFMA16(Al[0][1], P##h1, acc2_0);                          \
        acc1_1 = MFMA16(Ah[1][0], P##h0, acc1_1);                          \
        acc1_1 = MFMA16(Ah[1][1], P##h1, acc1_1);                          \
        acc2_1 = MFMA16(Ah[1][0], P##l0, acc2_1);                          \
        acc2_1 = MFMA16(Ah[1][1], P##l1, acc2_1);                          \
        acc2_1 = MFMA16(Al[1][0], P##h0, acc2_1);                          \
        acc2_1 = MFMA16(Al[1][1], P##h1, acc2_1);                          \
        const int k_ = (KT) * 16 + ci;                                     \
        const float cq_ = csq_s[k_];                                       \
        _Pragma("unroll")                                                  \
        for (int r = 0; r < 4; ++r) {                                      \
            float cross0 = acc1_0[r] + acc2_0[r] * (1.0f / 2048.0f);       \
            float d0 = cq_ - 2.0f * cross0;                                \
            if (d0 < d1v[0][r]) {                                          \
                d2v[0][r] = d1v[0][r];                                     \
                d1v[0][r] = d0; k1v[0][r] = k_;                            \
            } else if (d0 < d2v[0][r]) {                                   \
                d2v[0][r] = d0;                                            \
            }                                                              \
            float cross1 = acc1_1[r] + acc2_1[r] * (1.0f / 2048.0f);       \
            float d1 = cq_ - 2.0f * cross1;                                \
            if (d1 < d1v[1][r]) {                                          \
                d2v[1][r] = d1v[1][r];                                     \
                d1v[1][r] = d1; k1v[1][r] = k_;                            \
            } else if (d1 < d2v[1][r]) {                                   \
                d2v[1][r] = d1;                                            \
            }                                                              \
        }                                                                  \
    }

__global__ __launch_bounds__(256, 3) void pq_main_kernel(
    const float* __restrict__ x, const half8* __restrict__ whi,
    const half8* __restrict__ wlo, const float* __restrict__ csqg,
    const float* __restrict__ cbf, float* __restrict__ qout,
    float* __restrict__ idout)
{
    __shared__ float csq_s[KK];     // 1 KB
    __shared__ int   cand_k[BROWS]; // 512 B

    const int m   = blockIdx.y;
    const int n0  = blockIdx.x * BROWS;
    const int tid = threadIdx.x;
    const int w = tid >> 6, L = tid & 63;
    const int q = L >> 4, ci = L & 15;

    csq_s[tid] = csqg[m * KK + tid];

    // A fragments: d = t*32 + q*8 + j on BOTH operands -> k-slot permutation
    // cancels (same mapping on A and B).
    half8 Ah[2][2], Al[2][2];
#pragma unroll
    for (int rb = 0; rb < 2; ++rb) {
        int n = n0 + w * 32 + rb * 16 + ci;
        if (n > NN - 1) n = NN - 1;                    // tail clamp (writes guarded)
        const float4* xp = (const float4*)(x + (size_t)n * (MM * DD) + m * DD);
#pragma unroll
        for (int t = 0; t < 2; ++t) {
            float4 v0 = xp[t * 8 + q * 2 + 0];
            float4 v1 = xp[t * 8 + q * 2 + 1];
            float vs[8] = {v0.x, v0.y, v0.z, v0.w, v1.x, v1.y, v1.z, v1.w};
#pragma unroll
            for (int j = 0; j < 8; ++j) {
                _Float16 hi = (_Float16)vs[j];
                Ah[rb][t][j] = hi;
                Al[rb][t][j] = (_Float16)((vs[j] - (float)hi) * 2048.0f);
            }
        }
    }

    // per-lane best (d1,k1) and second-best value d2, per output row slot
    float d1v[2][4], d2v[2][4];
    int   k1v[2][4];
#pragma unroll
    for (int rb = 0; rb < 2; ++rb)
#pragma unroll
        for (int r = 0; r < 4; ++r) { d1v[rb][r] = 3.4e38f; d2v[rb][r] = 3.4e38f; k1v[rb][r] = 0; }

    // Per-lane B fragment pointers: c-chunk = q (low 32 dims) and 4+q (high).
    const half8* bh0p = whi + m * 2048 + q * 256;
    const half8* bh1p = whi + m * 2048 + (4 + q) * 256;
    const half8* bl0p = wlo + m * 2048 + q * 256;
    const half8* bl1p = wlo + m * 2048 + (4 + q) * 256;

    __syncthreads();                                   // csq_s ready

    const f32x4 z = {0.f, 0.f, 0.f, 0.f};

    // three named B-fragment sets, rotation mod 3; body kt uses s[kt%3] and
    // prefetches kt+2 into s[(kt+2)%3] (issued BEFORE the body's MFMAs).
    half8 s0h0, s0h1, s0l0, s0l1;
    half8 s1h0, s1h1, s1l0, s1l1;
    half8 s2h0, s2h1, s2l0, s2l1;

    PF(s0, 0)
    PF(s1, 1)

    PF(s2, 2)   BODY(s0, 0)
    PF(s0, 3)   BODY(s1, 1)
    PF(s1, 4)   BODY(s2, 2)
    PF(s2, 5)   BODY(s0, 3)
    PF(s0, 6)   BODY(s1, 4)
    PF(s1, 7)   BODY(s2, 5)
    PF(s2, 8)   BODY(s0, 6)
    PF(s0, 9)   BODY(s1, 7)
    PF(s1, 10)  BODY(s2, 8)
    PF(s2, 11)  BODY(s0, 9)
    PF(s0, 12)  BODY(s1, 10)
    PF(s1, 13)  BODY(s2, 11)
    PF(s2, 14)  BODY(s0, 12)
    PF(s0, 15)  BODY(s1, 13)
                BODY(s2, 14)
                BODY(s0, 15)

    // Finalize each of the 8 row-slots: butterfly argmin; near-ties -> exact
    // fp32 rescore (R1 arithmetic, empirically bit-matching numpy's argmin).
#pragma unroll
    for (int rb = 0; rb < 2; ++rb)
#pragma unroll
        for (int r = 0; r < 4; ++r) {
            float d = d1v[rb][r];
            int   k = k1v[rb][r];
            for (int mask = 1; mask < 16; mask <<= 1) {
                float ds = __shfl_xor(d, mask);
                int   ks = __shfl_xor(k, mask);
                if (ds < d || (ds == d && ks < k)) { d = ds; k = ks; }
            }
            const float thr = d + DELTA;               // d == dmin, uniform
            int cnt = (d1v[rb][r] <= thr ? 1 : 0) + (d2v[rb][r] <= thr ? 1 : 0);
            for (int mask = 1; mask < 16; mask <<= 1) cnt += __shfl_xor(cnt, mask);

            const int n = n0 + w * 32 + rb * 16 + q * 4 + r;
            if (cnt > 1 && n < NN) {                   // rare exact path (q-group uniform)
                const float* xr = x + (size_t)n * (MM * DD) + m * DD;
                float s0 = 0.f, s1 = 0.f, s2 = 0.f, s3 = 0.f;
                for (int dd = 0; dd < DD; dd += 4) {
                    s0 = fmaf(xr[dd + 0], xr[dd + 0], s0);
                    s1 = fmaf(xr[dd + 1], xr[dd + 1], s1);
                    s2 = fmaf(xr[dd + 2], xr[dd + 2], s2);
                    s3 = fmaf(xr[dd + 3], xr[dd + 3], s3);
                }
                const float xsq = (s0 + s1) + (s2 + s3);
                float bd = 3.4e38f; int bk = 0;
                for (int j = 0; j < 16; ++j) {         // lane ci: k = ci + 16j (ascending)
                    const int kk = ci + 16 * j;
                    const float* c0 = cbf + ((size_t)(m * KK + kk)) * DD;
                    float a0 = 0.f, a1 = 0.f;
                    for (int dd = 0; dd < DD; dd += 2) {
                        a0 = fmaf(c0[dd + 0], xr[dd + 0], a0);
                        a1 = fmaf(c0[dd + 1], xr[dd + 1], a1);
                    }
                    const float dist = (xsq - 2.f * (a0 + a1)) + csq_s[kk];
                    if (dist < bd) { bd = dist; bk = kk; }   // strict <, ascending k
                }
                for (int mask = 1; mask < 16; mask <<= 1) {
                    float db = __shfl_xor(bd, mask);
                    int   kb = __shfl_xor(bk, mask);
                    if (db < bd || (db == bd && kb < bk)) { bd = db; bk = kb; }
                }
                k = bk;
            }
            if (ci == r) cand_k[w * 32 + rb * 16 + q * 4 + r] = k;
        }
    __syncthreads();

    if (tid < BROWS) {
        int n = n0 + tid;
        if (n < NN) idout[(size_t)m * NN + n] = (float)cand_k[tid];
    }
    for (int i = 0; i < 8; ++i) {
        int row = i * 16 + (tid >> 4);
        int n = n0 + row;
        if (n < NN) {
            int k = cand_k[row];
            int j = tid & 15;
            float4 v = ((const float4*)cbf)[(m * KK + k) * 16 + j];
            ((float4*)(qout + (size_t)n * (MM * DD) + m * DD))[j] = v;
        }
    }
}

extern "C" void kernel_launch(void* const* d_in, const int* in_sizes, int n_in,
                              void* d_out, int out_size, void* d_ws, size_t ws_size,
                              hipStream_t stream)
{
    const float* x  = (const float*)d_in[0];
    const float* cb = (const float*)d_in[1];

    float* qout  = (float*)d_out;
    float* idout = qout + (size_t)NN * (MM * DD);

    half8* whi = (half8*)d_ws;
    half8* wlo = (half8*)((char*)d_ws + 256 * 1024);
    float* csq = (float*)((char*)d_ws + 512 * 1024);

    pq_prep_kernel<<<dim3(64), dim3(256), 0, stream>>>(cb, whi, wlo, csq);

    pq_main_kernel<<<dim3(NTILES, MM), dim3(256), 0, stream>>>(
        x, whi, wlo, csq, cb, qout, idout);
}